// Round 2
// baseline (32.131 us; speedup 1.0000x reference)
//
#include <hip/hip_runtime.h>

#define PATCHD 75
#define COUTD  16
#define HOUT   220
#define WOUT   220
#define HWD    (HOUT * WOUT)   // 48400
#define BD     2
#define NPOS   (BD * HWD)      // 96800
#define CPT    8               // channels per block (blockIdx.y selects group)

// ---------------------------------------------------------------------------
// Kernel A: build tables in d_ws.
// Layout per k (64 floats = 256 B):
//   tbl[k*64 +  0 + c] = exp(k1[k][c])            (a1)
//   tbl[k*64 + 16 + c] = k1[k][c]*exp(k1[k][c])   (b1)
//   tbl[k*64 + 32 + c] = exp(k2[k][c])            (a2)
//   tbl[k*64 + 48 + c] = k2[k][c]*exp(k2[k][c])   (b2)
// ---------------------------------------------------------------------------
__global__ void smorph_build_tables(const float* __restrict__ k1,
                                    const float* __restrict__ k2,
                                    float* __restrict__ tbl)
{
    int i = blockIdx.x * blockDim.x + threadIdx.x;
    if (i >= PATCHD * COUTD) return;
    int k = i >> 4;
    int c = i & 15;
    float v1 = k1[i];
    float e1 = __expf(v1);
    float v2 = k2[i];
    float e2 = __expf(v2);
    tbl[k * 64 +  0 + c] = e1;
    tbl[k * 64 + 16 + c] = v1 * e1;
    tbl[k * 64 + 32 + c] = e2;
    tbl[k * 64 + 48 + c] = v2 * e2;
}

// ---------------------------------------------------------------------------
// Kernel B: main loop. c0 is BLOCK-uniform (blockIdx.y), so all table reads
// have provably uniform addresses -> compiler emits s_load into SGPRs.
// Inner loop is then pure v_fma_f32 (1 SGPR operand each) + 1 global load
// + exp/rcp. No LDS at all.
// ---------------------------------------------------------------------------
__global__ __launch_bounds__(256)
void smorph_main(const float* __restrict__ x,
                 const float* __restrict__ tbl,
                 const float* __restrict__ bias,
                 float* __restrict__ out)
{
    const int c0 = (int)blockIdx.y * CPT;          // block-uniform channel base
    const int p  = (int)blockIdx.x * 256 + (int)threadIdx.x;
    if (p >= NPOS) return;

    const int b  = (p >= HWD) ? 1 : 0;             // batch index, no int divide
    const int hw = p - b * HWD;
    const float* xp = x + (size_t)b * PATCHD * HWD + hw;
    const float* t  = tbl + c0;                    // uniform base

    float num1[CPT], den1[CPT], num2[CPT], den2[CPT];
    #pragma unroll
    for (int j = 0; j < CPT; ++j) {
        num1[j] = 0.f; den1[j] = 0.f; num2[j] = 0.f; den2[j] = 0.f;
    }

    #pragma unroll 5
    for (int k = 0; k < PATCHD; ++k) {
        const float xv = xp[(size_t)k * HWD];       // coalesced vector load
        const float E  = __expf(xv);                // exp(x)
        const float R  = __builtin_amdgcn_rcpf(E);  // exp(-x)
        const float t1 = E * xv;
        const float t2 = -(R * xv);

        #pragma unroll
        for (int j = 0; j < CPT; ++j) {
            const float a1 = t[k * 64 +  0 + j];    // uniform -> SGPR
            const float b1 = t[k * 64 + 16 + j];
            const float a2 = t[k * 64 + 32 + j];
            const float b2 = t[k * 64 + 48 + j];
            // dir1: v = x + k1 : den += E*a1 ; num += (E*x)*a1 + E*b1
            den1[j] = fmaf(E,  a1, den1[j]);
            num1[j] = fmaf(t1, a1, num1[j]);
            num1[j] = fmaf(E,  b1, num1[j]);
            // dir2: v = -x + k2: den += R*a2 ; num += (-R*x)*a2 + R*b2
            den2[j] = fmaf(R,  a2, den2[j]);
            num2[j] = fmaf(t2, a2, num2[j]);
            num2[j] = fmaf(R,  b2, num2[j]);
        }
    }

    const size_t obase = (size_t)b * COUTD * HWD + hw;
    #pragma unroll
    for (int j = 0; j < CPT; ++j) {
        const int c = c0 + j;
        const float y = num1[j] * __builtin_amdgcn_rcpf(den1[j])
                      + num2[j] * __builtin_amdgcn_rcpf(den2[j])
                      + bias[c];
        out[obase + (size_t)c * HWD] = y;
    }
}

extern "C" void kernel_launch(void* const* d_in, const int* in_sizes, int n_in,
                              void* d_out, int out_size, void* d_ws, size_t ws_size,
                              hipStream_t stream)
{
    const float* x    = (const float*)d_in[0];
    const float* k1   = (const float*)d_in[1];
    const float* k2   = (const float*)d_in[2];
    const float* bias = (const float*)d_in[3];
    float* out = (float*)d_out;
    float* tbl = (float*)d_ws;                      // 75*64*4 = 19.2 KB scratch

    smorph_build_tables<<<dim3((PATCHD * COUTD + 255) / 256), 256, 0, stream>>>(k1, k2, tbl);

    dim3 grid((NPOS + 255) / 256, 2);
    smorph_main<<<grid, 256, 0, stream>>>(x, tbl, bias, out);
}